// Round 1
// baseline (272.674 us; speedup 1.0000x reference)
//
#include <hip/hip_runtime.h>
#include <stdint.h>
#include <stddef.h>

// Problem: z = x[32768,512] @ W[2048,512]^T + B; per-row instance-norm over 2048;
// out = (z_norm + y) * y.   All f32 in/out; GEMM internally bf16 MFMA.

typedef float f32x4_t __attribute__((ext_vector_type(4)));
typedef short short8_t __attribute__((ext_vector_type(8)));

#define BATCH   32768
#define INF     512
#define OUTF    2048
#define BM      32
#define THREADS 512
#define NSTEP   16                  // K / 32
#define WB_BYTES (OUTF * INF * 2)   // 2 MB bf16 W

__device__ __forceinline__ unsigned short f2bf(float f) {
    unsigned int u = __builtin_bit_cast(unsigned int, f);
    u += 0x7FFFu + ((u >> 16) & 1u);          // round-to-nearest-even
    return (unsigned short)(u >> 16);
}

__device__ __forceinline__ short8_t pack8(float4 a, float4 b) {
    short8_t v;
    v[0] = (short)f2bf(a.x); v[1] = (short)f2bf(a.y);
    v[2] = (short)f2bf(a.z); v[3] = (short)f2bf(a.w);
    v[4] = (short)f2bf(b.x); v[5] = (short)f2bf(b.y);
    v[6] = (short)f2bf(b.z); v[7] = (short)f2bf(b.w);
    return v;
}

// Prepass: W f32 [2048,512] -> Wb bf16 fragment-major: Wb[kk8][o][j] = W[o][kk8*8+j]
// (kk8 = k/8 plane). A lane's 16B B-frag load is then contiguous, and lanes 0..15
// of a quarter-wave read 256 contiguous bytes.
__global__ __launch_bounds__(256) void conv_w_kernel(const float* __restrict__ W,
                                                     unsigned short* __restrict__ Wb) {
    int id  = blockIdx.x * 256 + threadIdx.x;   // 0..131071  (o*64 + kk8)
    int o   = id >> 6;
    int kk8 = id & 63;
    const float* src = W + (size_t)o * INF + kk8 * 8;
    float4 a = *(const float4*)src;
    float4 b = *(const float4*)(src + 4);
    *(short8_t*)(Wb + (size_t)kk8 * (OUTF * 8) + o * 8) = pack8(a, b);
}

// Fused kernel. One block: 32 rows x 2048 cols. 8 waves; wave w owns cols [w*256, w*256+256).
// acc[mi][ni] is a 16x16 MFMA C-frag: z[m0 + mi*16 + (l>>4)*4 + q][w*256 + ni*16 + (l&15)].
template <bool USE_WB>
__global__ __launch_bounds__(THREADS, 2) void fused_kernel(
    const float* __restrict__ x, const float* __restrict__ y,
    const float* __restrict__ W, const float* __restrict__ Bias,
    const unsigned short* __restrict__ Wb, float* __restrict__ out) {

    // LDS layout:
    //   [0, 32768)        A tile, bf16, k8-major: addr = k8*512 + row*16   (K-loop)
    //   [0, 65664)        tbuf f32 [8][2052] (epilogue transpose, reused region)
    //   [65664, 67712)    stats  f32 [8 waves][32 rows][2]
    //   [67712, 67968)    rowstat f32 [32][2]  (mean, rstd)
    __shared__ __align__(16) char smem[67968];

    const int t   = threadIdx.x;
    const int w   = t >> 6;
    const int l   = t & 63;
    const int l15 = l & 15;
    const int lg  = l >> 4;
    const int m0  = blockIdx.x * BM;

    // ---- stage A (32x512 f32 -> bf16 LDS), coalesced: one wave reads one row ----
    #pragma unroll
    for (int i = 0; i < 4; ++i) {
        int id  = i * THREADS + t;
        int row = id >> 6;          // 0..31
        int k8  = id & 63;          // 0..63
        const float* src = x + (size_t)(m0 + row) * INF + k8 * 8;
        float4 a = *(const float4*)src;
        float4 b = *(const float4*)(src + 4);
        *(short8_t*)(smem + k8 * 512 + row * 16) = pack8(a, b);
    }
    __syncthreads();

    f32x4_t acc[2][16];
    #pragma unroll
    for (int mi = 0; mi < 2; ++mi)
        #pragma unroll
        for (int ni = 0; ni < 16; ++ni)
            acc[mi][ni] = (f32x4_t)(0.0f);

    // Per-lane bases.  A frag: lane l -> x[m0 + mi*16 + l15][s*32 + lg*8 .. +8]
    const char* aptr = smem + lg * 512 + l15 * 16;                    // + s*2048 + mi*256
    const unsigned short* wptr = nullptr;
    const float* wf = nullptr;
    if (USE_WB) wptr = Wb + ((size_t)lg << 14) + (size_t)(w * 256 + l15) * 8; // + s*65536 + ni*128
    else        wf   = W + (size_t)(w * 256 + l15) * INF + lg * 8;            // + ni*16*INF + s*32

    // ---- K loop: no barriers; W streamed from L2 directly to registers ----
    for (int s = 0; s < NSTEP; ++s) {
        short8_t a0 = *(const short8_t*)(aptr + s * 2048);
        short8_t a1 = *(const short8_t*)(aptr + s * 2048 + 256);
        #pragma unroll
        for (int ni = 0; ni < 16; ++ni) {
            short8_t bfr;
            if (USE_WB) {
                bfr = *(const short8_t*)(wptr + (size_t)s * 65536 + ni * 128);
            } else {
                const float* p = wf + (size_t)ni * 16 * INF + s * 32;
                float4 f0 = *(const float4*)p;
                float4 f1 = *(const float4*)(p + 4);
                bfr = pack8(f0, f1);
            }
            acc[0][ni] = __builtin_amdgcn_mfma_f32_16x16x32_bf16(a0, bfr, acc[0][ni], 0, 0, 0);
            acc[1][ni] = __builtin_amdgcn_mfma_f32_16x16x32_bf16(a1, bfr, acc[1][ni], 0, 0, 0);
        }
    }

    // ---- bias ----
    float biasv[16];
    #pragma unroll
    for (int ni = 0; ni < 16; ++ni)
        biasv[ni] = Bias[w * 256 + ni * 16 + l15];
    #pragma unroll
    for (int mi = 0; mi < 2; ++mi)
        #pragma unroll
        for (int ni = 0; ni < 16; ++ni)
            #pragma unroll
            for (int q = 0; q < 4; ++q)
                acc[mi][ni][q] += biasv[ni];

    float* stats   = (float*)(smem + 65664);   // [8][32][2]
    float* rowstat = (float*)(smem + 67712);   // [32][2]

    // ---- per-row sum / sumsq: lane partials over 16 ni, then 16-lane xor-reduce ----
    #pragma unroll
    for (int mi = 0; mi < 2; ++mi) {
        #pragma unroll
        for (int q = 0; q < 4; ++q) {
            float s1 = 0.f, s2 = 0.f;
            #pragma unroll
            for (int ni = 0; ni < 16; ++ni) {
                float v = acc[mi][ni][q];
                s1 += v; s2 += v * v;
            }
            #pragma unroll
            for (int d = 1; d < 16; d <<= 1) {
                s1 += __shfl_xor(s1, d);
                s2 += __shfl_xor(s2, d);
            }
            if (l15 == 0) {
                int r = mi * 16 + lg * 4 + q;
                stats[(w * 32 + r) * 2]     = s1;
                stats[(w * 32 + r) * 2 + 1] = s2;
            }
        }
    }
    __syncthreads();   // all waves done with K-loop (A region now free) + stats visible

    if (t < 32) {
        float s1 = 0.f, s2 = 0.f;
        #pragma unroll
        for (int wi = 0; wi < 8; ++wi) {
            s1 += stats[(wi * 32 + t) * 2];
            s2 += stats[(wi * 32 + t) * 2 + 1];
        }
        float mean = s1 * (1.0f / OUTF);
        float var  = s2 * (1.0f / OUTF) - mean * mean;
        rowstat[t * 2]     = mean;
        rowstat[t * 2 + 1] = rsqrtf(var + 1e-5f);
    }
    __syncthreads();

    // ---- epilogue: 4 phases of 8 rows; LDS transpose -> coalesced float4 y/out ----
    float* tbuf = (float*)smem;   // [8][2052]
    #pragma unroll
    for (int p = 0; p < 4; ++p) {
        const int mi = p >> 1;
        if ((lg >> 1) == (p & 1)) {          // this lane's rows fall in phase p
            #pragma unroll
            for (int ni = 0; ni < 16; ++ni)
                #pragma unroll
                for (int q = 0; q < 4; ++q)
                    tbuf[((lg & 1) * 4 + q) * 2052 + w * 256 + ni * 16 + l15] = acc[mi][ni][q];
        }
        __syncthreads();
        const int rbase = p * 8;
        #pragma unroll
        for (int i = 0; i < 8; ++i) {
            int r = rbase + i;
            float4 z4   = *(const float4*)(tbuf + i * 2052 + t * 4);
            float mean  = rowstat[r * 2];
            float rstd  = rowstat[r * 2 + 1];
            size_t grow = (size_t)(m0 + r) * OUTF;
            float4 yv   = *(const float4*)(y + grow + t * 4);
            float4 o4;
            float zn;
            zn = (z4.x - mean) * rstd; o4.x = (zn + yv.x) * yv.x;
            zn = (z4.y - mean) * rstd; o4.y = (zn + yv.y) * yv.y;
            zn = (z4.z - mean) * rstd; o4.z = (zn + yv.z) * yv.z;
            zn = (z4.w - mean) * rstd; o4.w = (zn + yv.w) * yv.w;
            *(float4*)(out + grow + t * 4) = o4;
        }
        __syncthreads();   // before next phase overwrites tbuf
    }
}

extern "C" void kernel_launch(void* const* d_in, const int* in_sizes, int n_in,
                              void* d_out, int out_size, void* d_ws, size_t ws_size,
                              hipStream_t stream) {
    const float* x = (const float*)d_in[0];
    const float* y = (const float*)d_in[1];
    const float* W = (const float*)d_in[2];
    const float* B = (const float*)d_in[3];
    float* out = (float*)d_out;

    if (ws_size >= (size_t)WB_BYTES) {
        unsigned short* Wb = (unsigned short*)d_ws;
        conv_w_kernel<<<512, 256, 0, stream>>>(W, Wb);
        fused_kernel<true><<<BATCH / BM, THREADS, 0, stream>>>(x, y, W, B, Wb, out);
    } else {
        fused_kernel<false><<<BATCH / BM, THREADS, 0, stream>>>(x, y, W, B, nullptr, out);
    }
}